// Round 7
// baseline (1513.702 us; speedup 1.0000x reference)
//
#include <hip/hip_runtime.h>

// Packed-sequence GRU decoder + fused log_softmax head, MFMA formulation, v6.
// T=512, B=1024, V=64, H=100.
//
// v6 structural change: BB 16 -> 2. 512 blocks x 512 threads => TWO blocks
// co-resident per CU (LDS 44KB, VGPR 92 <= 128 @ 4 waves/SIMD). The two
// blocks are barrier-independent, so one block's pointwise overlaps the
// other's MFMA/LDS phases -- attacks the phase-serialization that v3/v4/v5
// profiling showed (pipe-sum ~1700cy vs wall 3545cy). MFMA M-tile is padded
// (rows 2..15 zeroed once); matrix pipe had 8x headroom (MfmaUtil 6.4%).
//
// Per-block structure (unchanged from v5): waves 0..6 gate tiles via
// mfma_f32_16x16x32_f16, weights in registers, h in fp32 regs published as
// f16 hi+lo (split-float ~fp32 recurrence) to double-buffered LDS; wave 7
// stages x(t+1) (2-step-deep reg pipeline) and computes the output head
// (hi frags, DPP log_softmax, masked stores). One lgkm-only barrier/step.

#define T_STEPS 512
#define BATCH   1024
#define VOCAB   64
#define HID     100
#define BB      2       // batch rows per block (valid rows in the 16-row M-tile)
#define NKH     4       // h k-steps (K=128 padded; k==100 is bias column)
#define HSTR    136     // f16 row stride for h fragment buffers
#define XSTR    72      // f16 row stride for x fragment buffer (16B-aligned)

typedef _Float16 f16;
typedef _Float16 f16x8 __attribute__((ext_vector_type(8)));
typedef float    f32x4 __attribute__((ext_vector_type(4)));

#define MFMA(A_, B_, C_) __builtin_amdgcn_mfma_f32_16x16x32_f16((A_), (B_), (C_), 0, 0, 0)

__device__ __forceinline__ float rcp_f(float v)  { return __builtin_amdgcn_rcpf(v); }
__device__ __forceinline__ float sigm(float v)   { return rcp_f(1.0f + __expf(-v)); }
__device__ __forceinline__ float tanh_f(float v) { return 1.0f - 2.0f * rcp_f(__expf(2.0f * v) + 1.0f); }

// DPP lane move within the 16-lane row (VALU pipe; replaces ds_bpermute).
template<int CTRL>
__device__ __forceinline__ float dpp_mov(float v) {
    return __int_as_float(__builtin_amdgcn_update_dpp(
        0, __float_as_int(v), CTRL, 0xF, 0xF, true));
}
__device__ __forceinline__ float red_max16(float v) {
    v = fmaxf(v, dpp_mov<0xB1>(v));
    v = fmaxf(v, dpp_mov<0x4E>(v));
    v = fmaxf(v, dpp_mov<0x141>(v));
    v = fmaxf(v, dpp_mov<0x140>(v));
    return v;
}
__device__ __forceinline__ float red_sum16(float v) {
    v += dpp_mov<0xB1>(v);
    v += dpp_mov<0x4E>(v);
    v += dpp_mov<0x141>(v);
    v += dpp_mov<0x140>(v);
    return v;
}

// Barrier that only orders LDS: no vmcnt(0) drain.
__device__ __forceinline__ void sync_lds() {
    __builtin_amdgcn_sched_barrier(0);
    asm volatile("s_waitcnt lgkmcnt(0)" ::: "memory");
    __builtin_amdgcn_s_barrier();
    __builtin_amdgcn_sched_barrier(0);
}

// Head-wave x staging: lane l covers batch-row (l>>2), cols (l&3)*16..+15.
// Only lanes with xrow < BB participate.
#define HLOADX(P0, P1, P2, P3, tt) do {                                     \
    const float* xp_ = x + ((size_t)(tt) * BATCH + rowbase + xrow) * VOCAB + xcol; \
    P0 = *reinterpret_cast<const float4*>(xp_);                             \
    P1 = *reinterpret_cast<const float4*>(xp_ + 4);                         \
    P2 = *reinterpret_cast<const float4*>(xp_ + 8);                         \
    P3 = *reinterpret_cast<const float4*>(xp_ + 12);                        \
} while (0)
#define HSTAGEX(P0, P1, P2, P3, buf) do {                                   \
    f16x8 a_, b_;                                                           \
    a_[0]=(f16)P0.x; a_[1]=(f16)P0.y; a_[2]=(f16)P0.z; a_[3]=(f16)P0.w;     \
    a_[4]=(f16)P1.x; a_[5]=(f16)P1.y; a_[6]=(f16)P1.z; a_[7]=(f16)P1.w;     \
    b_[0]=(f16)P2.x; b_[1]=(f16)P2.y; b_[2]=(f16)P2.z; b_[3]=(f16)P2.w;     \
    b_[4]=(f16)P3.x; b_[5]=(f16)P3.y; b_[6]=(f16)P3.z; b_[7]=(f16)P3.w;     \
    *reinterpret_cast<f16x8*>(&xs[buf][xrow][xcol])     = a_;               \
    *reinterpret_cast<f16x8*>(&xs[buf][xrow][xcol + 8]) = b_;               \
} while (0)

__global__ __launch_bounds__(512, 4) void gru_mfma(
    const float* __restrict__ x, const float* __restrict__ h0,
    const int* __restrict__ lengths,
    const float* __restrict__ W_ih, const float* __restrict__ W_hh,
    const float* __restrict__ b_ih, const float* __restrict__ b_hh,
    const float* __restrict__ W_out, const float* __restrict__ b_out,
    float* __restrict__ out)
{
    const int tid = threadIdx.x;
    const int w   = tid >> 6;        // wave 0..7
    const int l   = tid & 63;
    const int c   = l & 15;          // frag col (A batch-row / B gate or vocab col)
    const int lg  = l >> 4;          // lane group 0..3
    const int rowbase = blockIdx.x * BB;

    __shared__ alignas(16) f16 hHi[2][16 * HSTR];
    __shared__ alignas(16) f16 hLo[2][16 * HSTR];
    __shared__ alignas(16) f16 xs[2][16][XSTR];   // x_t fragments (f16)

    // Union'd weight fragments:
    //   waves 0..6: wf[s*4+ks]   = W_hh^T frags (s=r/z/n; +bias col k=100)
    //               wf[12+s*2+ks]= W_ih^T frags
    //   wave 7:     wf[v*4+ks]   = W_out^T frags for vocab tile v (+b_out col)
    f16x8 wf[18];
    float bin = 0.f;        // b_ih(n) for this lane's gate col
    float hold[BB];         // fp32 hidden owned by lg==0 threads (rows 0..BB-1)
    int   lenv[BB];

    #pragma unroll
    for (int r = 0; r < BB; ++r) lenv[r] = lengths[rowbase + r];

    if (w < 7) {
        const int gl = 16 * w + c;
        const bool gv = gl < HID;
        #pragma unroll
        for (int s = 0; s < 3; ++s) {
            const int g = s * HID + gl;
            #pragma unroll
            for (int ks = 0; ks < NKH; ++ks) {
                f16x8 v;
                #pragma unroll
                for (int j = 0; j < 8; ++j) {
                    const int k = ks * 32 + lg * 8 + j;
                    float val = 0.f;
                    if (gv) {
                        if (k < HID)        val = W_hh[(size_t)g * HID + k];
                        else if (k == HID)  val = (s < 2) ? (b_ih[g] + b_hh[g]) : b_hh[g];
                    }
                    v[j] = (f16)val;
                }
                wf[s * 4 + ks] = v;
            }
            #pragma unroll
            for (int ks = 0; ks < 2; ++ks) {
                f16x8 v;
                #pragma unroll
                for (int j = 0; j < 8; ++j) {
                    const int k = ks * 32 + lg * 8 + j;
                    v[j] = (f16)(gv ? W_ih[(size_t)g * VOCAB + k] : 0.f);
                }
                wf[12 + s * 2 + ks] = v;
            }
        }
        bin = gv ? b_ih[2 * HID + gl] : 0.f;

        // initial hidden: fp32 regs (lg==0 lanes) + hi/lo frags into buffer 0
        #pragma unroll
        for (int r = 0; r < BB; ++r) {
            float hv = (gv && lg == 0) ? h0[(size_t)(rowbase + r) * HID + gl] : 0.f;
            hold[r] = hv;
            if (gv && lg == 0) {
                f16 hi = (f16)hv;
                hHi[0][r * HSTR + gl] = hi;
                hLo[0][r * HSTR + gl] = (f16)(hv - (float)hi);
            }
        }
    } else {
        #pragma unroll
        for (int vt = 0; vt < 4; ++vt) {
            const int vr = 16 * vt + c;      // vocab row of W_out
            #pragma unroll
            for (int ks = 0; ks < NKH; ++ks) {
                f16x8 v;
                #pragma unroll
                for (int j = 0; j < 8; ++j) {
                    const int k = ks * 32 + lg * 8 + j;
                    float val = 0.f;
                    if (k < HID)        val = W_out[(size_t)vr * HID + k];
                    else if (k == HID)  val = b_out[vr];
                    v[j] = (f16)val;
                }
                wf[vt * 4 + ks] = v;
            }
        }
        #pragma unroll
        for (int r = 0; r < BB; ++r) hold[r] = 0.f;
    }

    // Zero the padded M-tile rows (and k>=HID of the valid rows); bias col.
    if (tid < 16) {
        const int row = tid;
        const int k0 = (row < BB) ? HID : 0;   // valid rows: only pad cols
        for (int k = k0; k < 128; ++k) {
            hHi[0][row * HSTR + k] = (f16)0.f;  hLo[0][row * HSTR + k] = (f16)0.f;
            hHi[1][row * HSTR + k] = (f16)0.f;  hLo[1][row * HSTR + k] = (f16)0.f;
        }
        if (row < BB) {
            hHi[0][row * HSTR + HID] = (f16)1.0f;   // bias column (both buffers)
            hHi[1][row * HSTR + HID] = (f16)1.0f;
        } else {
            // zero the x rows >= BB (cols 0..63), both buffers
            for (int k = 0; k < VOCAB; ++k) {
                xs[0][row][k] = (f16)0.f;
                xs[1][row][k] = (f16)0.f;
            }
        }
    }

    // Head-wave x pipeline: qA = x(t+1) on even t, qB = x(t+2) -- ~2 steps
    // of HBM latency in flight. Lanes with xrow < BB only.
    const int xrow = l >> 2;
    const int xcol = (l & 3) * 16;
    float4 qA0, qA1, qA2, qA3, qB0, qB1, qB2, qB3;
    if (w == 7 && xrow < BB) {
        HLOADX(qA0, qA1, qA2, qA3, 0);
        HSTAGEX(qA0, qA1, qA2, qA3, 0);      // xs[0] = x(0)
        HLOADX(qA0, qA1, qA2, qA3, 1);       // in flight
        HLOADX(qB0, qB1, qB2, qB3, 2);       // in flight
    }
    __syncthreads();   // prologue: full barrier once is fine

    // Loop runs one extra iteration: gate waves act for t<T, head for t>0.
    for (int t = 0; t <= T_STEPS; ++t) {
        const int cur = t & 1;               // buf[cur] holds h_{t-1}
        if (w < 7) {
            if (t < T_STEPS) {
                // x fragments from LDS (staged by head wave last step)
                f16x8 xq0 = *reinterpret_cast<const f16x8*>(&xs[cur][c][lg * 8]);
                f16x8 xq1 = *reinterpret_cast<const f16x8*>(&xs[cur][c][32 + lg * 8]);
                // h fragments
                f16x8 hh[NKH], hl[NKH];
                #pragma unroll
                for (int ks = 0; ks < NKH; ++ks) {
                    const int off = c * HSTR + ks * 32 + lg * 8;
                    hh[ks] = *reinterpret_cast<const f16x8*>(&hHi[cur][off]);
                    hl[ks] = *reinterpret_cast<const f16x8*>(&hLo[cur][off]);
                }

                f32x4 zz = {0.f, 0.f, 0.f, 0.f};
                f32x4 aRa = zz, aZa = zz;
                f32x4 aNX = {bin, bin, bin, bin};   // seed with b_ih(n): kills adds
                f32x4 aRb = zz, aZb = zz, aNHa = zz, aNHb = zz;
                __builtin_amdgcn_s_setprio(1);
                aRa = MFMA(xq0, wf[12], aRa);
                aZa = MFMA(xq0, wf[14], aZa);
                aNX = MFMA(xq0, wf[16], aNX);
                aRa = MFMA(xq1, wf[13], aRa);
                aZa = MFMA(xq1, wf[15], aZa);
                aNX = MFMA(xq1, wf[17], aNX);
                #pragma unroll
                for (int ks = 0; ks < NKH; ++ks) {
                    aRa  = MFMA(hh[ks], wf[0 + ks], aRa);
                    aRb  = MFMA(hl[ks], wf[0 + ks], aRb);
                    aZa  = MFMA(hh[ks], wf[4 + ks], aZa);
                    aZb  = MFMA(hl[ks], wf[4 + ks], aZb);
                    aNHa = MFMA(hh[ks], wf[8 + ks], aNHa);
                    aNHb = MFMA(hl[ks], wf[8 + ks], aNHb);
                }
                __builtin_amdgcn_s_setprio(0);

                // pointwise for valid rows r<BB (registers of C rows lg*4+r;
                // only lg==0 results are real and published)
                const int kk = 16 * w + c;
                const bool pub = (kk < HID) && (lg == 0);
                #pragma unroll
                for (int r = 0; r < BB; ++r) {
                    float rg   = sigm(aRa[r] + aRb[r]);
                    float zg   = sigm(aZa[r] + aZb[r]);
                    float ng   = tanh_f(fmaf(rg, aNHa[r] + aNHb[r], aNX[r]));
                    float hnew = fmaf(zg, hold[r] - ng, ng);   // (1-z)n + z*h
                    float hv   = (t < lenv[r]) ? hnew : hold[r];
                    hold[r] = hv;
                    if (pub) {
                        f16 hi = (f16)hv;
                        hHi[cur ^ 1][r * HSTR + kk] = hi;
                        hLo[cur ^ 1][r * HSTR + kk] = (f16)(hv - (float)hi);
                    }
                }
            }
        } else {
            // (a) stage x(t+1) into xs[(t+1)&1]; refill the reg slot with x(t+3)
            if (t < T_STEPS && xrow < BB) {
                const int tt = (t + 3 < T_STEPS) ? t + 3 : T_STEPS - 1;
                if ((t & 1) == 0) {
                    HSTAGEX(qA0, qA1, qA2, qA3, 1);
                    HLOADX(qA0, qA1, qA2, qA3, tt);
                } else {
                    HSTAGEX(qB0, qB1, qB2, qB3, 0);
                    HLOADX(qB0, qB1, qB2, qB3, tt);
                }
            }
            // (b) head over h_{t-1} (HI fragments only) -> output row t-1
            if (t > 0) {
                const int tp = t - 1;
                f16x8 hh[NKH];
                #pragma unroll
                for (int ks = 0; ks < NKH; ++ks) {
                    const int off = c * HSTR + ks * 32 + lg * 8;
                    hh[ks] = *reinterpret_cast<const f16x8*>(&hHi[cur][off]);
                }
                f32x4 zz = {0.f, 0.f, 0.f, 0.f};
                f32x4 a0 = zz, a1 = zz, a2 = zz, a3 = zz;
                #pragma unroll
                for (int ks = 0; ks < NKH; ++ks) {
                    a0 = MFMA(hh[ks], wf[0  + ks], a0);
                    a1 = MFMA(hh[ks], wf[4  + ks], a1);
                    a2 = MFMA(hh[ks], wf[8  + ks], a2);
                    a3 = MFMA(hh[ks], wf[12 + ks], a3);
                }
                #pragma unroll
                for (int r = 0; r < BB; ++r) {
                    float v0 = a0[r], v1 = a1[r], v2 = a2[r], v3 = a3[r];
                    float m = red_max16(fmaxf(fmaxf(v0, v1), fmaxf(v2, v3)));
                    float s = red_sum16(__expf(v0 - m) + __expf(v1 - m)
                                      + __expf(v2 - m) + __expf(v3 - m));
                    float ls = m + __logf(s);
                    if (lg == 0) {   // row r valid only in lane-group 0
                        const bool act = tp < lenv[r];
                        float* orow = out + ((size_t)tp * BATCH + rowbase + r) * VOCAB + c;
                        orow[ 0] = act ? (v0 - ls) : 0.f;
                        orow[16] = act ? (v1 - ls) : 0.f;
                        orow[32] = act ? (v2 - ls) : 0.f;
                        orow[48] = act ? (v3 - ls) : 0.f;
                    }
                }
            }
        }
        sync_lds();
    }
}

extern "C" void kernel_launch(void* const* d_in, const int* in_sizes, int n_in,
                              void* d_out, int out_size, void* d_ws, size_t ws_size,
                              hipStream_t stream) {
    const float* x     = (const float*)d_in[0];
    const float* h0    = (const float*)d_in[1];
    const int*   lens  = (const int*)  d_in[2];
    const float* W_ih  = (const float*)d_in[3];
    const float* W_hh  = (const float*)d_in[4];
    const float* b_ih  = (const float*)d_in[5];
    const float* b_hh  = (const float*)d_in[6];
    const float* W_out = (const float*)d_in[7];
    const float* b_out = (const float*)d_in[8];
    float* outp = (float*)d_out;

    gru_mfma<<<BATCH / BB, 512, 0, stream>>>(x, h0, lens, W_ih, W_hh,
                                             b_ih, b_hh, W_out, b_out, outp);
}